// Round 10
// baseline (127.396 us; speedup 1.0000x reference)
//
#include <hip/hip_runtime.h>
#include <math.h>

// Round-10 = round-9 bit-identical arithmetic; ONLY the launch-bounds change.
// Round-9 finding: VGPR_Count=64 while peak liveness is >=72 (pk[24]+vx[24]+
// vy[24] live through extract-min) -> the (256,2) min-waves hint made the
// allocator squeeze arch-VGPRs and pay AGPR-copy/remat tax on every payload
// access (~1.7k extra inst-eq/thread, the measured 3.9k vs ~2.2k static).
// Round 2 with plain __launch_bounds__(256) allocated 144 VGPRs — that is
// the behavior we want; at VALU-bound + deep ILP, 3-4 waves/SIMD suffice.
// FROZEN (bit-critical, round-7 lesson): atan2f/cosf/sinf + __f*_rn corner
// chain, mask ratios, masked sx/sy sum order, centroid FDIV.
// Register-only dataflow (round-4 lesson: no LDS).

#define FMUL __fmul_rn
#define FADD __fadd_rn
#define FSUB __fsub_rn
#define FDIV __fdiv_rn

__device__ __forceinline__ float rcpf_(float x) { return __builtin_amdgcn_rcpf(x); }

__global__ __launch_bounds__(256)
void riou_kernel(const float* __restrict__ pred,
                 const float* __restrict__ tgt,
                 float* __restrict__ out, int n)
{
    int i = blockIdx.x * blockDim.x + threadIdx.x;
    if (i >= n) return;

    const float2* p2 = (const float2*)(pred + 6 * (size_t)i);
    const float2* q2 = (const float2*)(tgt  + 6 * (size_t)i);
    float2 pa = p2[0], pb = p2[1], pc2 = p2[2];
    float2 qa = q2[0], qb = q2[1], qc2 = q2[2];
    const float px = pa.x, py = pa.y, pw = pb.x, ph = pb.y;
    const float qx = qa.x, qy = qa.y, qw = qb.x, qh = qb.y;

    // bit-critical transcendental sequence — DO NOT substitute identities
    float rad1 = atan2f(pc2.x, pc2.y);
    float cA = cosf(rad1), sA = sinf(rad1);
    float rad2 = atan2f(qc2.x, qc2.y);
    float cB = cosf(rad2), sB = sinf(rad2);

    const float ddx[4] = {0.5f, -0.5f, -0.5f, 0.5f};
    const float ddy[4] = {0.5f, 0.5f, -0.5f, -0.5f};
    float c1x[4], c1y[4], c2x[4], c2y[4];
#pragma unroll
    for (int j = 0; j < 4; j++) {
        float cx = FMUL(ddx[j], pw), cy = FMUL(ddy[j], ph);
        c1x[j] = FADD(FSUB(FMUL(cx, cA), FMUL(cy, sA)), px);
        c1y[j] = FADD(FADD(FMUL(cx, sA), FMUL(cy, cA)), py);
        float dx2 = FMUL(ddx[j], qw), dy2 = FMUL(ddy[j], qh);
        c2x[j] = FADD(FSUB(FMUL(dx2, cB), FMUL(dy2, sB)), qx);
        c2y[j] = FADD(FADD(FMUL(dx2, sB), FMUL(dy2, cB)), qy);
    }

    // enclosing-box diagonal + center distance
    float minx = c1x[0], maxx = c1x[0], miny = c1y[0], maxy = c1y[0];
#pragma unroll
    for (int j = 1; j < 4; j++) {
        minx = fminf(minx, c1x[j]); maxx = fmaxf(maxx, c1x[j]);
        miny = fminf(miny, c1y[j]); maxy = fmaxf(maxy, c1y[j]);
    }
#pragma unroll
    for (int j = 0; j < 4; j++) {
        minx = fminf(minx, c2x[j]); maxx = fmaxf(maxx, c2x[j]);
        miny = fminf(miny, c2y[j]); maxy = fmaxf(maxy, c2y[j]);
    }
    float wcb = FSUB(maxx, minx), hcb = FSUB(maxy, miny);
    float c2d = FADD(FMUL(wcb, wcb), FMUL(hcb, hcb));
    float dxc = FSUB(px, qx), dyc = FSUB(py, qy);
    float d2 = FADD(FMUL(dxc, dxc), FMUL(dyc, dyc));

    // ---- phase 1: 24 candidate slots, mask bits + masked sums ----
    float vx[24], vy[24];
    unsigned mbits = 0;
    float sx = 0.0f, sy = 0.0f;
    const float eps = 1e-6f;
    const float hieps = 1.0f + 1e-6f;

    // slots 0-3: c1 corners inside c2
    {
        float ax = c2x[0], ay = c2y[0];
        float abx = FSUB(c2x[1], ax), aby = FSUB(c2y[1], ay);
        float adx = FSUB(c2x[3], ax), ady = FSUB(c2y[3], ay);
        float rab = rcpf_(FADD(FMUL(abx, abx), FMUL(aby, aby)));
        float rad = rcpf_(FADD(FMUL(adx, adx), FMUL(ady, ady)));
#pragma unroll
        for (int j = 0; j < 4; j++) {
            float amx = FSUB(c1x[j], ax), amy = FSUB(c1y[j], ay);
            float pab = FMUL(FADD(FMUL(abx, amx), FMUL(aby, amy)), rab);
            float pad = FMUL(FADD(FMUL(adx, amx), FMUL(ady, amy)), rad);
            int m = (pab > -eps) & (pab < hieps) & (pad > -eps) & (pad < hieps);
            vx[j] = c1x[j]; vy[j] = c1y[j];
            mbits |= (unsigned)m << j;
            sx = FADD(sx, m ? c1x[j] : 0.0f);
            sy = FADD(sy, m ? c1y[j] : 0.0f);
        }
    }
    // slots 4-7: c2 corners inside c1
    {
        float ax = c1x[0], ay = c1y[0];
        float abx = FSUB(c1x[1], ax), aby = FSUB(c1y[1], ay);
        float adx = FSUB(c1x[3], ax), ady = FSUB(c1y[3], ay);
        float rab = rcpf_(FADD(FMUL(abx, abx), FMUL(aby, aby)));
        float rad = rcpf_(FADD(FMUL(adx, adx), FMUL(ady, ady)));
#pragma unroll
        for (int j = 0; j < 4; j++) {
            float amx = FSUB(c2x[j], ax), amy = FSUB(c2y[j], ay);
            float pab = FMUL(FADD(FMUL(abx, amx), FMUL(aby, amy)), rab);
            float pad = FMUL(FADD(FMUL(adx, amx), FMUL(ady, amy)), rad);
            int m = (pab > -eps) & (pab < hieps) & (pad > -eps) & (pad < hieps);
            vx[4 + j] = c2x[j]; vy[4 + j] = c2y[j];
            mbits |= (unsigned)m << (4 + j);
            sx = FADD(sx, m ? c2x[j] : 0.0f);
            sy = FADD(sy, m ? c2y[j] : 0.0f);
        }
    }
    // slots 8-23: edge intersections; den_u = -den_t exactly -> one rcp.
    float fex[4], fey[4];
#pragma unroll
    for (int e2 = 0; e2 < 4; e2++) {
        fex[e2] = FSUB(c2x[(e2 + 1) & 3], c2x[e2]);
        fey[e2] = FSUB(c2y[(e2 + 1) & 3], c2y[e2]);
    }
#pragma unroll
    for (int e1 = 0; e1 < 4; e1++) {
        float x1 = c1x[e1], y1 = c1y[e1];
        float ex = FSUB(c1x[(e1 + 1) & 3], x1), ey = FSUB(c1y[(e1 + 1) & 3], y1);
#pragma unroll
        for (int e2 = 0; e2 < 4; e2++) {
            float dx31 = FSUB(c2x[e2], x1), dy31 = FSUB(c2y[e2], y1);
            float num_t = FSUB(FMUL(ex, dy31), FMUL(ey, dx31));
            float den_t = FSUB(FMUL(ey, fex[e2]), FMUL(ex, fey[e2]));
            float rd = rcpf_(den_t);          // den==0 -> inf -> masked below
            float tq = FMUL(num_t, rd);
            float num_u = FSUB(FMUL(fey[e2], dx31), FMUL(fex[e2], dy31));
            float uq = FMUL(num_u, rd);       // == -u exactly
            int m = (tq > 0.0f) & (tq < 1.0f) & (uq < 0.0f) & (uq > -1.0f);
            float ix = FADD(x1, FMUL(tq, ex));   // garbage if masked; gated
            float iy = FADD(y1, FMUL(tq, ey));
            int s = 8 + 4 * e1 + e2;
            vx[s] = ix; vy[s] = iy;
            mbits |= (unsigned)m << s;
            sx = FADD(sx, m ? ix : 0.0f);
            sy = FADD(sy, m ? iy : 0.0f);
        }
    }

    int k = __popc(mbits);

    // centroid (IEEE div: feeds every recentered coordinate — bit-frozen)
    float kk = (float)(k > 0 ? k : 1);
    float mx = FDIV(sx, kk), my = FDIV(sy, kk);

    // ---- phase 2: recenter + u32 packed keys (27-bit angle | 5-bit slot) ----
    // Masked slots keep garbage coords (never selected: when s<k a genuine
    // un-extracted key always beats masked; when s>=k payload gated to prev).
    unsigned pk[24];
#pragma unroll
    for (int j = 0; j < 24; j++) {
        int m = (mbits >> j) & 1u;
        float wx2 = FSUB(vx[j], mx);
        float wy2 = FSUB(vy[j], my);
        vx[j] = wx2; vy[j] = wy2;
        float dsum = FADD(fabsf(wx2), fabsf(wy2));
        float rs = (dsum > 0.0f) ? FMUL(wx2, rcpf_(dsum)) : 1.0f;
        float keyf = copysignf(FSUB(1.0f, rs), wy2);   // monotone in atan2
        unsigned sb = __float_as_uint(keyf);
        unsigned u = sb ^ (unsigned)(((int)sb >> 31) | (int)0x80000000);
        pk[j] = m ? ((u & 0xFFFFFFE0u) | (unsigned)j)
                  : (0xFFFFFFE0u | (unsigned)j);       // masked: sorts last
    }

    // ---- phase 3: rotation-based extract-min, 4 chains of 6 + combine ----
    // w[j] = pk[j] - (prevkey+1) mod 2^32 preserves circular order (all keys
    // span < 2^31): un-extracted real < masked < wrapped-extracted. One cmp.
    unsigned prevkey = 0xFFFFFFFFu;   // poff = 0 on pass 0 -> w = pk
    float firstx = 0.0f, firsty = 0.0f, prevx = 0.0f, prevy = 0.0f;
    float crs = 0.0f;
#pragma unroll
    for (int s = 0; s < 8; s++) {
        unsigned poff = prevkey + 1u;
        unsigned cb0, cb1, cb2, cb3;
        float cxx0, cxx1, cxx2, cxx3, cyy0, cyy1, cyy2, cyy3;
#pragma unroll
        for (int c = 0; c < 4; c++) {
            unsigned b = pk[6 * c] - poff;
            float bx = vx[6 * c], by = vy[6 * c];
#pragma unroll
            for (int t = 1; t < 6; t++) {
                int j = 6 * c + t;
                unsigned wj = pk[j] - poff;
                bool lt = wj < b;
                b  = lt ? wj : b;
                bx = lt ? vx[j] : bx;
                by = lt ? vy[j] : by;
            }
            if (c == 0) { cb0 = b; cxx0 = bx; cyy0 = by; }
            else if (c == 1) { cb1 = b; cxx1 = bx; cyy1 = by; }
            else if (c == 2) { cb2 = b; cxx2 = bx; cyy2 = by; }
            else { cb3 = b; cxx3 = bx; cyy3 = by; }
        }
        bool l01 = cb1 < cb0;
        unsigned b01 = l01 ? cb1 : cb0;
        float x01 = l01 ? cxx1 : cxx0, y01 = l01 ? cyy1 : cyy0;
        bool l23 = cb3 < cb2;
        unsigned b23 = l23 ? cb3 : cb2;
        float x23 = l23 ? cxx3 : cxx2, y23 = l23 ? cyy3 : cyy2;
        bool lf = b23 < b01;
        unsigned bw = lf ? b23 : b01;
        float bx = lf ? x23 : x01, by = lf ? y23 : y01;
        unsigned bestkey = bw + poff;
        bool act = s < k;              // inactive pass: payload -> prev
        bx = act ? bx : prevx;
        by = act ? by : prevy;
        if (s == 0) { firstx = bx; firsty = by; }
        else {
            // inactive: cross(prev,prev) = exact IEEE 0 (identical products)
            crs = FADD(crs, FSUB(FMUL(prevx, by), FMUL(prevy, bx)));
        }
        prevx = bx; prevy = by; prevkey = bestkey;
    }
    // rare tail: noise masks can push k past the geometric bound of 8
    for (int s = 8; s < k; s++) {
        unsigned poff = prevkey + 1u;
        unsigned best = pk[0] - poff;
        float bx = vx[0], by = vy[0];
#pragma unroll
        for (int j = 1; j < 24; j++) {
            unsigned wj = pk[j] - poff;
            bool lt = wj < best;
            best = lt ? wj : best;
            bx = lt ? vx[j] : bx;
            by = lt ? vy[j] : by;
        }
        crs = FADD(crs, FSUB(FMUL(prevx, by), FMUL(prevy, bx)));
        prevx = bx; prevy = by; prevkey = best + poff;
    }
    // close the ring
    crs = FADD(crs, FSUB(FMUL(prevx, firsty), FMUL(prevy, firstx)));
    float inter = FMUL(0.5f, fabsf(crs));

    float area1 = FMUL(pw, ph), area2 = FMUL(qw, qh);
    float uni = FSUB(FADD(area1, area2), inter);
    float iou = FMUL(inter, rcpf_(uni));

    out[i] = FADD(FSUB(1.0f, iou), FMUL(d2, rcpf_(c2d)));
}

extern "C" void kernel_launch(void* const* d_in, const int* in_sizes, int n_in,
                              void* d_out, int out_size, void* d_ws, size_t ws_size,
                              hipStream_t stream) {
    const float* pred = (const float*)d_in[0];
    const float* tgt  = (const float*)d_in[1];
    float* out = (float*)d_out;
    int n = in_sizes[0] / 6;
    int block = 256;
    int grid = (n + block - 1) / block;
    riou_kernel<<<grid, block, 0, stream>>>(pred, tgt, out, n);
}

// Round 11
// 127.166 us; speedup vs baseline: 1.0018x; 1.0018x over previous
//
#include <hip/hip_runtime.h>
#include <math.h>

// Round-11 = round-9/10 bit-identical arithmetic; allocation-only change.
// Evidence chain: VGPR_Count pinned at 64 across launch-bound variants
// (r9: (256,2), r10: plain) while liveness >= 85 (pk[24]+vx[24]+vy[24]+
// scalars) and occupancy ~35% (~192 regs/wave-equivalent on the unified
// file) -> backend spills the arrays to AGPRs (v_accvgpr copy per access)
// or remats, the measured ~1.5k extra inst-eq/thread. The allocator's
// occupancy target (8 waves/EU -> 64 VGPRs) is the cause; the source-level
// override is amdgpu_waves_per_eu(1): allocator freed to keep arrays in
// arch VGPRs (~100-170), occupancy 12-20 waves/CU (>= today's effective).
// FROZEN (bit-critical, round-7 lesson): atan2f/cosf/sinf + __f*_rn corner
// chain, mask ratios, masked sx/sy sum order, centroid FDIV.
// Register-only dataflow (round-4 lesson: no LDS).

#define FMUL __fmul_rn
#define FADD __fadd_rn
#define FSUB __fsub_rn
#define FDIV __fdiv_rn

__device__ __forceinline__ float rcpf_(float x) { return __builtin_amdgcn_rcpf(x); }

__global__
__attribute__((amdgpu_flat_work_group_size(256, 256), amdgpu_waves_per_eu(1)))
void riou_kernel(const float* __restrict__ pred,
                 const float* __restrict__ tgt,
                 float* __restrict__ out, int n)
{
    int i = blockIdx.x * blockDim.x + threadIdx.x;
    if (i >= n) return;

    const float2* p2 = (const float2*)(pred + 6 * (size_t)i);
    const float2* q2 = (const float2*)(tgt  + 6 * (size_t)i);
    float2 pa = p2[0], pb = p2[1], pc2 = p2[2];
    float2 qa = q2[0], qb = q2[1], qc2 = q2[2];
    const float px = pa.x, py = pa.y, pw = pb.x, ph = pb.y;
    const float qx = qa.x, qy = qa.y, qw = qb.x, qh = qb.y;

    // bit-critical transcendental sequence — DO NOT substitute identities
    float rad1 = atan2f(pc2.x, pc2.y);
    float cA = cosf(rad1), sA = sinf(rad1);
    float rad2 = atan2f(qc2.x, qc2.y);
    float cB = cosf(rad2), sB = sinf(rad2);

    const float ddx[4] = {0.5f, -0.5f, -0.5f, 0.5f};
    const float ddy[4] = {0.5f, 0.5f, -0.5f, -0.5f};
    float c1x[4], c1y[4], c2x[4], c2y[4];
#pragma unroll
    for (int j = 0; j < 4; j++) {
        float cx = FMUL(ddx[j], pw), cy = FMUL(ddy[j], ph);
        c1x[j] = FADD(FSUB(FMUL(cx, cA), FMUL(cy, sA)), px);
        c1y[j] = FADD(FADD(FMUL(cx, sA), FMUL(cy, cA)), py);
        float dx2 = FMUL(ddx[j], qw), dy2 = FMUL(ddy[j], qh);
        c2x[j] = FADD(FSUB(FMUL(dx2, cB), FMUL(dy2, sB)), qx);
        c2y[j] = FADD(FADD(FMUL(dx2, sB), FMUL(dy2, cB)), qy);
    }

    // enclosing-box diagonal + center distance
    float minx = c1x[0], maxx = c1x[0], miny = c1y[0], maxy = c1y[0];
#pragma unroll
    for (int j = 1; j < 4; j++) {
        minx = fminf(minx, c1x[j]); maxx = fmaxf(maxx, c1x[j]);
        miny = fminf(miny, c1y[j]); maxy = fmaxf(maxy, c1y[j]);
    }
#pragma unroll
    for (int j = 0; j < 4; j++) {
        minx = fminf(minx, c2x[j]); maxx = fmaxf(maxx, c2x[j]);
        miny = fminf(miny, c2y[j]); maxy = fmaxf(maxy, c2y[j]);
    }
    float wcb = FSUB(maxx, minx), hcb = FSUB(maxy, miny);
    float c2d = FADD(FMUL(wcb, wcb), FMUL(hcb, hcb));
    float dxc = FSUB(px, qx), dyc = FSUB(py, qy);
    float d2 = FADD(FMUL(dxc, dxc), FMUL(dyc, dyc));

    // ---- phase 1: 24 candidate slots, mask bits + masked sums ----
    float vx[24], vy[24];
    unsigned mbits = 0;
    float sx = 0.0f, sy = 0.0f;
    const float eps = 1e-6f;
    const float hieps = 1.0f + 1e-6f;

    // slots 0-3: c1 corners inside c2
    {
        float ax = c2x[0], ay = c2y[0];
        float abx = FSUB(c2x[1], ax), aby = FSUB(c2y[1], ay);
        float adx = FSUB(c2x[3], ax), ady = FSUB(c2y[3], ay);
        float rab = rcpf_(FADD(FMUL(abx, abx), FMUL(aby, aby)));
        float rad = rcpf_(FADD(FMUL(adx, adx), FMUL(ady, ady)));
#pragma unroll
        for (int j = 0; j < 4; j++) {
            float amx = FSUB(c1x[j], ax), amy = FSUB(c1y[j], ay);
            float pab = FMUL(FADD(FMUL(abx, amx), FMUL(aby, amy)), rab);
            float pad = FMUL(FADD(FMUL(adx, amx), FMUL(ady, amy)), rad);
            int m = (pab > -eps) & (pab < hieps) & (pad > -eps) & (pad < hieps);
            vx[j] = c1x[j]; vy[j] = c1y[j];
            mbits |= (unsigned)m << j;
            sx = FADD(sx, m ? c1x[j] : 0.0f);
            sy = FADD(sy, m ? c1y[j] : 0.0f);
        }
    }
    // slots 4-7: c2 corners inside c1
    {
        float ax = c1x[0], ay = c1y[0];
        float abx = FSUB(c1x[1], ax), aby = FSUB(c1y[1], ay);
        float adx = FSUB(c1x[3], ax), ady = FSUB(c1y[3], ay);
        float rab = rcpf_(FADD(FMUL(abx, abx), FMUL(aby, aby)));
        float rad = rcpf_(FADD(FMUL(adx, adx), FMUL(ady, ady)));
#pragma unroll
        for (int j = 0; j < 4; j++) {
            float amx = FSUB(c2x[j], ax), amy = FSUB(c2y[j], ay);
            float pab = FMUL(FADD(FMUL(abx, amx), FMUL(aby, amy)), rab);
            float pad = FMUL(FADD(FMUL(adx, amx), FMUL(ady, amy)), rad);
            int m = (pab > -eps) & (pab < hieps) & (pad > -eps) & (pad < hieps);
            vx[4 + j] = c2x[j]; vy[4 + j] = c2y[j];
            mbits |= (unsigned)m << (4 + j);
            sx = FADD(sx, m ? c2x[j] : 0.0f);
            sy = FADD(sy, m ? c2y[j] : 0.0f);
        }
    }
    // slots 8-23: edge intersections; den_u = -den_t exactly -> one rcp.
    float fex[4], fey[4];
#pragma unroll
    for (int e2 = 0; e2 < 4; e2++) {
        fex[e2] = FSUB(c2x[(e2 + 1) & 3], c2x[e2]);
        fey[e2] = FSUB(c2y[(e2 + 1) & 3], c2y[e2]);
    }
#pragma unroll
    for (int e1 = 0; e1 < 4; e1++) {
        float x1 = c1x[e1], y1 = c1y[e1];
        float ex = FSUB(c1x[(e1 + 1) & 3], x1), ey = FSUB(c1y[(e1 + 1) & 3], y1);
#pragma unroll
        for (int e2 = 0; e2 < 4; e2++) {
            float dx31 = FSUB(c2x[e2], x1), dy31 = FSUB(c2y[e2], y1);
            float num_t = FSUB(FMUL(ex, dy31), FMUL(ey, dx31));
            float den_t = FSUB(FMUL(ey, fex[e2]), FMUL(ex, fey[e2]));
            float rd = rcpf_(den_t);          // den==0 -> inf -> masked below
            float tq = FMUL(num_t, rd);
            float num_u = FSUB(FMUL(fey[e2], dx31), FMUL(fex[e2], dy31));
            float uq = FMUL(num_u, rd);       // == -u exactly
            int m = (tq > 0.0f) & (tq < 1.0f) & (uq < 0.0f) & (uq > -1.0f);
            float ix = FADD(x1, FMUL(tq, ex));   // garbage if masked; gated
            float iy = FADD(y1, FMUL(tq, ey));
            int s = 8 + 4 * e1 + e2;
            vx[s] = ix; vy[s] = iy;
            mbits |= (unsigned)m << s;
            sx = FADD(sx, m ? ix : 0.0f);
            sy = FADD(sy, m ? iy : 0.0f);
        }
    }

    int k = __popc(mbits);

    // centroid (IEEE div: feeds every recentered coordinate — bit-frozen)
    float kk = (float)(k > 0 ? k : 1);
    float mx = FDIV(sx, kk), my = FDIV(sy, kk);

    // ---- phase 2: recenter + u32 packed keys (27-bit angle | 5-bit slot) ----
    // Masked slots keep garbage coords (never selected: when s<k a genuine
    // un-extracted key always beats masked; when s>=k payload gated to prev).
    unsigned pk[24];
#pragma unroll
    for (int j = 0; j < 24; j++) {
        int m = (mbits >> j) & 1u;
        float wx2 = FSUB(vx[j], mx);
        float wy2 = FSUB(vy[j], my);
        vx[j] = wx2; vy[j] = wy2;
        float dsum = FADD(fabsf(wx2), fabsf(wy2));
        float rs = (dsum > 0.0f) ? FMUL(wx2, rcpf_(dsum)) : 1.0f;
        float keyf = copysignf(FSUB(1.0f, rs), wy2);   // monotone in atan2
        unsigned sb = __float_as_uint(keyf);
        unsigned u = sb ^ (unsigned)(((int)sb >> 31) | (int)0x80000000);
        pk[j] = m ? ((u & 0xFFFFFFE0u) | (unsigned)j)
                  : (0xFFFFFFE0u | (unsigned)j);       // masked: sorts last
    }

    // ---- phase 3: rotation-based extract-min, 4 chains of 6 + combine ----
    // w[j] = pk[j] - (prevkey+1) mod 2^32 preserves circular order (all keys
    // span < 2^31): un-extracted real < masked < wrapped-extracted. One cmp.
    unsigned prevkey = 0xFFFFFFFFu;   // poff = 0 on pass 0 -> w = pk
    float firstx = 0.0f, firsty = 0.0f, prevx = 0.0f, prevy = 0.0f;
    float crs = 0.0f;
#pragma unroll
    for (int s = 0; s < 8; s++) {
        unsigned poff = prevkey + 1u;
        unsigned cb0, cb1, cb2, cb3;
        float cxx0, cxx1, cxx2, cxx3, cyy0, cyy1, cyy2, cyy3;
#pragma unroll
        for (int c = 0; c < 4; c++) {
            unsigned b = pk[6 * c] - poff;
            float bx = vx[6 * c], by = vy[6 * c];
#pragma unroll
            for (int t = 1; t < 6; t++) {
                int j = 6 * c + t;
                unsigned wj = pk[j] - poff;
                bool lt = wj < b;
                b  = lt ? wj : b;
                bx = lt ? vx[j] : bx;
                by = lt ? vy[j] : by;
            }
            if (c == 0) { cb0 = b; cxx0 = bx; cyy0 = by; }
            else if (c == 1) { cb1 = b; cxx1 = bx; cyy1 = by; }
            else if (c == 2) { cb2 = b; cxx2 = bx; cyy2 = by; }
            else { cb3 = b; cxx3 = bx; cyy3 = by; }
        }
        bool l01 = cb1 < cb0;
        unsigned b01 = l01 ? cb1 : cb0;
        float x01 = l01 ? cxx1 : cxx0, y01 = l01 ? cyy1 : cyy0;
        bool l23 = cb3 < cb2;
        unsigned b23 = l23 ? cb3 : cb2;
        float x23 = l23 ? cxx3 : cxx2, y23 = l23 ? cyy3 : cyy2;
        bool lf = b23 < b01;
        unsigned bw = lf ? b23 : b01;
        float bx = lf ? x23 : x01, by = lf ? y23 : y01;
        unsigned bestkey = bw + poff;
        bool act = s < k;              // inactive pass: payload -> prev
        bx = act ? bx : prevx;
        by = act ? by : prevy;
        if (s == 0) { firstx = bx; firsty = by; }
        else {
            // inactive: cross(prev,prev) = exact IEEE 0 (identical products)
            crs = FADD(crs, FSUB(FMUL(prevx, by), FMUL(prevy, bx)));
        }
        prevx = bx; prevy = by; prevkey = bestkey;
    }
    // rare tail: noise masks can push k past the geometric bound of 8
    for (int s = 8; s < k; s++) {
        unsigned poff = prevkey + 1u;
        unsigned best = pk[0] - poff;
        float bx = vx[0], by = vy[0];
#pragma unroll
        for (int j = 1; j < 24; j++) {
            unsigned wj = pk[j] - poff;
            bool lt = wj < best;
            best = lt ? wj : best;
            bx = lt ? vx[j] : bx;
            by = lt ? vy[j] : by;
        }
        crs = FADD(crs, FSUB(FMUL(prevx, by), FMUL(prevy, bx)));
        prevx = bx; prevy = by; prevkey = best + poff;
    }
    // close the ring
    crs = FADD(crs, FSUB(FMUL(prevx, firsty), FMUL(prevy, firstx)));
    float inter = FMUL(0.5f, fabsf(crs));

    float area1 = FMUL(pw, ph), area2 = FMUL(qw, qh);
    float uni = FSUB(FADD(area1, area2), inter);
    float iou = FMUL(inter, rcpf_(uni));

    out[i] = FADD(FSUB(1.0f, iou), FMUL(d2, rcpf_(c2d)));
}

extern "C" void kernel_launch(void* const* d_in, const int* in_sizes, int n_in,
                              void* d_out, int out_size, void* d_ws, size_t ws_size,
                              hipStream_t stream) {
    const float* pred = (const float*)d_in[0];
    const float* tgt  = (const float*)d_in[1];
    float* out = (float*)d_out;
    int n = in_sizes[0] / 6;
    int block = 256;
    int grid = (n + block - 1) / block;
    riou_kernel<<<grid, block, 0, stream>>>(pred, tgt, out, n);
}